// Round 6
// baseline (166.957 us; speedup 1.0000x reference)
//
#include <hip/hip_runtime.h>

#define NSZ   192
#define NSZ2  (NSZ*NSZ)
#define NSZ3  (NSZ*NSZ*NSZ)
#define N1    191
#define TW    64
#define TH    12
#define TD    8
#define LROWS 15              // value rows h0-1 .. h0+13 (row-clamped => replicated)
#define PADW  72              // LDS row floats; LDS col c <-> global col w0-4+c
#define ROWF4 18
#define SLOTF4 810            // float4 per slot (3ch * 15 rows * 18)
#define SLOTF  (SLOTF4*4)     // 3240 floats per slot
#define NTHREADS 192

__device__ __forceinline__ void gload_lds16(const float* g, float* l) {
    __builtin_amdgcn_global_load_lds((const __attribute__((address_space(1))) void*)g,
                                     (__attribute__((address_space(3))) void*)l, 16, 0, 0);
}

__device__ __forceinline__ void ld12(float* d, const float* p) {
    *(float4*)&d[0] = *(const float4*)&p[0];
    *(float4*)&d[4] = *(const float4*)&p[4];
    *(float4*)&d[8] = *(const float4*)&p[8];
}

// stage one y-slice (3ch x 15 rows x 72 cols, clamped) into an LDS slot via
// async global->LDS DMA. LDS f4 index == tid + k*192 (linear, DMA contract).
__device__ __forceinline__ void stage(const float* __restrict__ y, float* slot,
                                      int s, const int* goff, int tid) {
    const float* src = y + (size_t)s * NSZ2;
    gload_lds16(src + goff[0], slot + (size_t)tid * 4);
    gload_lds16(src + goff[1], slot + (size_t)(tid + 192) * 4);
    gload_lds16(src + goff[2], slot + (size_t)(tid + 384) * 4);
    gload_lds16(src + goff[3], slot + (size_t)(tid + 576) * 4);
    if (tid < SLOTF4 - 768)   // 42 remaining chunks
        gload_lds16(src + goff[4], slot + (size_t)(tid + 768) * 4);
}

#define IDX(c,dir,q) (((c)*3+(dir))*4+(q))

// box-sum of 4 sliding windows over 6 masked |diff| values, shared-pair FMA form
#define WSUM_MASKED(d, t0, t1, t2, t3)                              \
    {   float e12 = fmaf(colv[2], fabsf(d[2]), colv[1] * fabsf(d[1])); \
        float e34 = fmaf(colv[4], fabsf(d[4]), colv[3] * fabsf(d[3])); \
        t0 = fmaf(colv[0], fabsf(d[0]), e12);                       \
        t1 = fmaf(colv[3], fabsf(d[3]), e12);                       \
        t2 = fmaf(colv[2], fabsf(d[2]), e34);                       \
        t3 = fmaf(colv[5], fabsf(d[5]), e34); }

__global__ __launch_bounds__(NTHREADS, 3)
void jac_kernel(const float* __restrict__ y, float* __restrict__ out) {
    __shared__ __align__(16) float lds[3 * SLOTF];

    const int tx = threadIdx.x;          // 0..15, owns 4 output cols
    const int ty = threadIdx.y;          // 0..11, owns 1 output row
    const int tid = ty * 16 + tx;
    const int w0 = blockIdx.x * TW;
    const int h0 = blockIdx.y * TH;
    const int d0 = blockIdx.z * TD;
    const int j  = h0 + ty;
    const int k0 = w0 + 4 * tx;

    // validity masks: filter cols gk = k0-1+p (p=0..5), filter rows gr = j-1+r
    float colv[6], rowv[3];
    #pragma unroll
    for (int p = 0; p < 6; ++p) {
        int gk = k0 - 1 + p;
        colv[p] = (gk >= 0 && gk < N1) ? 1.f : 0.f;
    }
    #pragma unroll
    for (int r = 0; r < 3; ++r) {
        int gr = j - 1 + r;
        rowv[r] = (gr >= 0 && gr < N1) ? 1.f : 0.f;
    }

    // staging source offsets (slice-invariant), computed once
    int goff[5];
    #pragma unroll
    for (int k = 0; k < 5; ++k) {
        int e4 = tid + k * NTHREADS;
        if (e4 > SLOTF4 - 1) e4 = SLOTF4 - 1;
        int rowidx = e4 / ROWF4;
        int m   = e4 - rowidx * ROWF4;
        int ch  = rowidx / LROWS;
        int row = rowidx - ch * LROWS;
        int gr = h0 - 1 + row; gr = gr < 0 ? 0 : (gr > N1 ? N1 : gr);
        int c4 = w0 - 4 + 4 * m; c4 = c4 < 0 ? 0 : (c4 > NSZ - 4 ? NSZ - 4 : c4);
        goff[k] = ch * NSZ3 + gr * NSZ + c4;
    }

    // d-ring (pair-sum form): a1 = acc(i-1), b = acc(i-1)+acc(i-2)
    // f(i-1) = b + acc(i);  b' = a1 + acc(i);  a1' = acc(i)
    float a1[36], b[36];
    #pragma unroll
    for (int t = 0; t < 36; ++t) { a1[t] = 0.f; b[t] = 0.f; }

    // prologue: stage slices d0-1 (if exists) and d0
    if (d0 >= 1) stage(y, lds + ((d0 + 2) % 3) * SLOTF, d0 - 1, goff, tid);
    stage(y, lds + (d0 % 3) * SLOTF, d0, goff, tid);
    __syncthreads();

    int sA = (d0 + 2) % 3;               // slot of slice i = d0-1
    const int wbase = 4 * tx;            // b128-aligned window base word in row

    for (int ii = 0; ii < TD + 2; ++ii) {
        const int i  = d0 - 1 + ii;
        const int sB = sA == 2 ? 0 : sA + 1;
        const int sC = sB == 2 ? 0 : sB + 1;

        // issue async staging of slice i+2 into sC (in flight across compute)
        if (ii <= TD && i + 2 <= N1)
            stage(y, lds + sC * SLOTF, i + 2, goff, tid);

        float f[36];

        if (i >= 0 && i < N1) {          // uniform: diff slice i exists
            #pragma unroll
            for (int c = 0; c < 3; ++c) {
                const float* pA = lds + sA * SLOTF + (c * LROWS + ty) * PADW + wbase;
                const float* pB = lds + sB * SLOTF + (c * LROWS + ty) * PADW + wbase;
                float acc[12];
                float A0[12], A1[12], B0[12];
                ld12(A0, pA);                       // value row j-1 @ slice i
                #pragma unroll
                for (int r = 0; r < 3; ++r) {       // filter rows gr = j-1+r
                    ld12(A1, pA + (r + 1) * PADW);  // value row gr+1 @ slice i
                    ld12(B0, pB + r * PADW);        // value row gr   @ slice i+1
                    const float rv = rowv[r];
                    // filter col gk = k0-1+p <-> window index p+3
                    float dH[6], dD[6], dW[6];
                    #pragma unroll
                    for (int p = 0; p < 6; ++p) {
                        dH[p] = A1[p + 3] - A0[p + 3];
                        dD[p] = B0[p + 3] - A0[p + 3];
                        dW[p] = A0[p + 4] - A0[p + 3];
                    }
                    float h0s, h1s, h2s, h3s, d0s, d1s, d2s, d3s, w0s, w1s, w2s, w3s;
                    WSUM_MASKED(dH, h0s, h1s, h2s, h3s)   // row-mask not needed (row clamp => 0)
                    WSUM_MASKED(dD, d0s, d1s, d2s, d3s)
                    WSUM_MASKED(dW, w0s, w1s, w2s, w3s)
                    if (r == 0) {
                        acc[0] = h0s;      acc[1] = h1s;      acc[2] = h2s;      acc[3] = h3s;
                        acc[4] = rv * d0s; acc[5] = rv * d1s; acc[6] = rv * d2s; acc[7] = rv * d3s;
                        acc[8] = rv * w0s; acc[9] = rv * w1s; acc[10] = rv * w2s; acc[11] = rv * w3s;
                    } else {
                        acc[0] += h0s; acc[1] += h1s; acc[2] += h2s; acc[3] += h3s;
                        acc[4] = fmaf(rv, d0s, acc[4]); acc[5] = fmaf(rv, d1s, acc[5]);
                        acc[6] = fmaf(rv, d2s, acc[6]); acc[7] = fmaf(rv, d3s, acc[7]);
                        acc[8] = fmaf(rv, w0s, acc[8]); acc[9] = fmaf(rv, w1s, acc[9]);
                        acc[10] = fmaf(rv, w2s, acc[10]); acc[11] = fmaf(rv, w3s, acc[11]);
                    }
                    #pragma unroll
                    for (int p = 0; p < 12; ++p) A0[p] = A1[p];
                }
                // fold into d-ring (per channel)
                #pragma unroll
                for (int t = 0; t < 12; ++t) {
                    const int gi = c * 12 + t;
                    const float ac = acc[t];
                    f[gi]  = b[gi] + ac;
                    b[gi]  = a1[gi] + ac;
                    a1[gi] = ac;
                }
            }
        } else {                         // acc == 0: rotate ring with zeros
            #pragma unroll
            for (int t = 0; t < 36; ++t) {
                f[t]  = b[t];
                b[t]  = a1[t];
                a1[t] = 0.f;
            }
        }

        const int d = i - 1;
        if (ii >= 2 && d < N1 && j < N1) {
            const float K = 27.f, KS = 1.f / 19683.f;   // det scaled by 27^3
            #pragma unroll
            for (int q = 0; q < 4; ++q) {
                if (k0 + q < N1) {
                    float ayx = f[IDX(0,0,q)], ayy = f[IDX(0,1,q)], ayz = f[IDX(0,2,q)];
                    float axx = f[IDX(1,0,q)], axy = f[IDX(1,1,q)], axz = f[IDX(1,2,q)];
                    float azx = f[IDX(2,0,q)], azy = f[IDX(2,1,q)], azz = f[IDX(2,2,q)];
                    float ayy27 = ayy + K, azz27 = azz + K, axx27 = axx + K;
                    float t = fmaf(-ayz, azy, ayy27 * azz27);
                    float v = fmaf(-ayz, azx, ayx * azz27);
                    float w = fmaf(-ayy27, azx, ayx * azy);
                    float R = axx27 * t;
                    R = fmaf(-axy, v, R);
                    R = fmaf(axz, w, R);
                    out[(d * N1 + j) * N1 + (k0 + q)] = R * KS;
                }
            }
        }

        __syncthreads();                 // drains vmcnt: staged slice i+2 ready
        sA = sB;
    }
}

extern "C" void kernel_launch(void* const* d_in, const int* in_sizes, int n_in,
                              void* d_out, int out_size, void* d_ws, size_t ws_size,
                              hipStream_t stream) {
    const float* y = (const float*)d_in[0];
    float* out = (float*)d_out;
    dim3 grid(3, 16, 24);     // w-tiles, h-tiles, d-chunks
    dim3 block(16, 12, 1);
    jac_kernel<<<grid, block, 0, stream>>>(y, out);
}

// Round 7
// 65.218 us; speedup vs baseline: 2.5600x; 2.5600x over previous
//
#include <hip/hip_runtime.h>

#define NSZ   192
#define NSZ2  (NSZ*NSZ)
#define NSZ3  (NSZ*NSZ*NSZ)
#define N1    191
#define TW    64
#define TH    8
#define TD    16
#define LROWS 11              // value rows h0-1 .. h0+9 (clamped)
#define PADW  72              // LDS row floats; LDS col c <-> global col w0-4+c
#define ROWF4 18
#define SLOTF4 594            // 3ch * 11 rows * 18 f4
#define SLOTF  (SLOTF4*4)     // 2376 floats per slice slot (9504 B)
#define NTHREADS 256

__device__ __forceinline__ void gload_lds16(const float* g, float* l) {
    __builtin_amdgcn_global_load_lds((const __attribute__((address_space(1))) void*)g,
                                     (__attribute__((address_space(3))) void*)l, 16, 0, 0);
}

__device__ __forceinline__ void ld3f2(float* d, const float* p) {
    *(float2*)&d[0] = *(const float2*)&p[0];
    *(float2*)&d[2] = *(const float2*)&p[2];
    *(float2*)&d[4] = *(const float2*)&p[4];
}

// stage one y-slice (3ch x 11 rows x 72 cols, clamped) via async global->LDS DMA
__device__ __forceinline__ void stage(const float* __restrict__ y, float* slot,
                                      int s, const int* goff, int tid) {
    const float* src = y + (size_t)s * NSZ2;
    gload_lds16(src + goff[0], slot + (size_t)tid * 4);
    gload_lds16(src + goff[1], slot + (size_t)(tid + 256) * 4);
    if (tid < SLOTF4 - 512)   // 82 tail chunks
        gload_lds16(src + goff[2], slot + (size_t)(tid + 512) * 4);
}

// one filter row: w-box-sums (2 output cols) of col-masked |diffs|.
// dH needs no row mask (row-clamp replication zeroes it at edges);
// dD/dW are row-masked via rv at the accumulate.
#define ROWC(A0, A1, B, rv, FIRST)                                               \
    {   float dh0=A1[1]-A0[1], dh1=A1[2]-A0[2], dh2=A1[3]-A0[3], dh3=A1[4]-A0[4];\
        float dd0=B[1]-A0[1],  dd1=B[2]-A0[2],  dd2=B[3]-A0[3],  dd3=B[4]-A0[4]; \
        float dw0=A0[2]-A0[1], dw1=A0[3]-A0[2], dw2=A0[4]-A0[3], dw3=A0[5]-A0[4];\
        float eH = fmaf(colv[2], fabsf(dh2), colv[1]*fabsf(dh1));                \
        float tH0 = fmaf(colv[0], fabsf(dh0), eH);                               \
        float tH1 = fmaf(colv[3], fabsf(dh3), eH);                               \
        float eD = fmaf(colv[2], fabsf(dd2), colv[1]*fabsf(dd1));                \
        float tD0 = fmaf(colv[0], fabsf(dd0), eD);                               \
        float tD1 = fmaf(colv[3], fabsf(dd3), eD);                               \
        float eW = fmaf(colv[2], fabsf(dw2), colv[1]*fabsf(dw1));                \
        float tW0 = fmaf(colv[0], fabsf(dw0), eW);                               \
        float tW1 = fmaf(colv[3], fabsf(dw3), eW);                               \
        if (FIRST) { aH0=tH0; aH1=tH1; aD0=rv*tD0; aD1=rv*tD1;                   \
                     aW0=rv*tW0; aW1=rv*tW1; }                                   \
        else { aH0+=tH0; aH1+=tH1; aD0=fmaf(rv,tD0,aD0); aD1=fmaf(rv,tD1,aD1);   \
               aW0=fmaf(rv,tW0,aW0); aW1=fmaf(rv,tW1,aW1); } }

__global__ __launch_bounds__(NTHREADS, 2)
void jac_kernel(const float* __restrict__ y, float* __restrict__ out) {
    __shared__ __align__(16) float lds[3 * SLOTF];

    const int tx = threadIdx.x;          // 0..31, owns 2 output cols
    const int ty = threadIdx.y;          // 0..7, owns 1 output row
    const int tid = ty * 32 + tx;
    const int w0 = blockIdx.x * TW;
    const int h0 = blockIdx.y * TH;
    const int d0 = blockIdx.z * TD;
    const int j  = h0 + ty;
    const int k0 = w0 + 2 * tx;

    // masks: filter cols gk = k0-1+p (p=0..3), filter rows gr = j-1+r
    float colv[4], rowv[3];
    #pragma unroll
    for (int p = 0; p < 4; ++p) { int gk = k0 - 1 + p; colv[p] = (gk >= 0 && gk < N1) ? 1.f : 0.f; }
    #pragma unroll
    for (int r = 0; r < 3; ++r) { int gr = j - 1 + r; rowv[r] = (gr >= 0 && gr < N1) ? 1.f : 0.f; }

    // staging source offsets (slice-invariant)
    int goff[3];
    #pragma unroll
    for (int k = 0; k < 3; ++k) {
        int e4 = tid + k * 256; if (e4 > SLOTF4 - 1) e4 = SLOTF4 - 1;
        int rowi = e4 / ROWF4, m = e4 - rowi * ROWF4;
        int ch = rowi / LROWS, rr = rowi - ch * LROWS;
        int gr = h0 - 1 + rr; gr = gr < 0 ? 0 : (gr > N1 ? N1 : gr);
        int c4 = w0 - 4 + 4 * m; c4 = c4 < 0 ? 0 : (c4 > NSZ - 4 ? NSZ - 4 : c4);
        goff[k] = ch * NSZ3 + gr * NSZ + c4;
    }

    // d-ring: a1 = acc(i-1), bb = acc(i-1)+acc(i-2); f(i-1) = bb + acc(i)
    float a1[18], bb[18];
    #pragma unroll
    for (int t = 0; t < 18; ++t) { a1[t] = 0.f; bb[t] = 0.f; }

    if (d0 >= 1) stage(y, lds + ((d0 + 2) % 3) * SLOTF, d0 - 1, goff, tid);
    stage(y, lds + (d0 % 3) * SLOTF, d0, goff, tid);
    __syncthreads();

    const int rowoff = ty * PADW + 2 * tx + 2;   // window float offset in slot

    // carried A-windows: rows j-1..j+1 of the current A-slice, per channel
    float c[3][3][6];
    {
        const float* base = lds + (((d0 >= 1) ? (d0 - 1) : d0) % 3) * SLOTF + rowoff;
        #pragma unroll
        for (int ch = 0; ch < 3; ++ch) {
            const float* p = base + ch * (LROWS * PADW);
            ld3f2(c[ch][0], p);
            ld3f2(c[ch][1], p + PADW);
            ld3f2(c[ch][2], p + 2 * PADW);
        }
    }

    float* pa = lds + ((d0 + 2) % 3) * SLOTF;    // slice i
    float* pb = lds + (d0 % 3) * SLOTF;          // slice i+1
    float* pc = lds + ((d0 + 1) % 3) * SLOTF;    // stage dest (slice i+2)

    #pragma unroll 3
    for (int ii = 0; ii < TD + 2; ++ii) {
        const int i = d0 - 1 + ii;

        if (ii <= TD && i + 2 <= N1) stage(y, pc, i + 2, goff, tid);

        float f[18];
        if (i >= 0 && i < N1) {          // uniform: diff slice i exists
            #pragma unroll
            for (int ch = 0; ch < 3; ++ch) {
                const float* bA = pa + ch * (LROWS * PADW) + rowoff;
                const float* bB = pb + ch * (LROWS * PADW) + rowoff;
                float a3[6];
                ld3f2(a3, bA + 3 * PADW);           // only NEW A-row (j+2)
                float b0[6], b1[6], b2[6];
                ld3f2(b0, bB); ld3f2(b1, bB + PADW); ld3f2(b2, bB + 2 * PADW);
                float aH0, aH1, aD0, aD1, aW0, aW1;
                ROWC(c[ch][0], c[ch][1], b0, rowv[0], 1)
                ROWC(c[ch][1], c[ch][2], b1, rowv[1], 0)
                ROWC(c[ch][2], a3,       b2, rowv[2], 0)
                const int gi = ch * 6;
                f[gi+0]=bb[gi+0]+aH0; bb[gi+0]=a1[gi+0]+aH0; a1[gi+0]=aH0;
                f[gi+1]=bb[gi+1]+aH1; bb[gi+1]=a1[gi+1]+aH1; a1[gi+1]=aH1;
                f[gi+2]=bb[gi+2]+aD0; bb[gi+2]=a1[gi+2]+aD0; a1[gi+2]=aD0;
                f[gi+3]=bb[gi+3]+aD1; bb[gi+3]=a1[gi+3]+aD1; a1[gi+3]=aD1;
                f[gi+4]=bb[gi+4]+aW0; bb[gi+4]=a1[gi+4]+aW0; a1[gi+4]=aW0;
                f[gi+5]=bb[gi+5]+aW1; bb[gi+5]=a1[gi+5]+aW1; a1[gi+5]=aW1;
                #pragma unroll
                for (int p = 0; p < 6; ++p) {        // carry B -> next iter's A
                    c[ch][0][p] = b0[p]; c[ch][1][p] = b1[p]; c[ch][2][p] = b2[p];
                }
            }
        } else {                          // acc == 0: rotate ring
            #pragma unroll
            for (int t = 0; t < 18; ++t) { f[t] = bb[t]; bb[t] = a1[t]; a1[t] = 0.f; }
        }

        const int d = i - 1;
        if (ii >= 2 && d < N1 && j < N1) {
            const float K = 27.f, KS = 1.f / 19683.f;   // det scaled by 27^3
            #pragma unroll
            for (int q = 0; q < 2; ++q) {
                if (k0 + q < N1) {
                    float ayx = f[0+q],  ayy = f[2+q],  ayz = f[4+q];
                    float axx = f[6+q],  axy = f[8+q],  axz = f[10+q];
                    float azx = f[12+q], azy = f[14+q], azz = f[16+q];
                    float ayyK = ayy + K, azzK = azz + K, axxK = axx + K;
                    float t = fmaf(-ayz, azy, ayyK * azzK);
                    float v = fmaf(-ayz, azx, ayx * azzK);
                    float w = fmaf(-ayyK, azx, ayx * azy);
                    float R = axxK * t;
                    R = fmaf(-axy, v, R);
                    R = fmaf(axz, w, R);
                    out[(d * N1 + j) * N1 + (k0 + q)] = R * KS;
                }
            }
        }

        __syncthreads();                 // drains DMA; orders slot reuse
        float* tp = pa; pa = pb; pb = pc; pc = tp;
    }
}

extern "C" void kernel_launch(void* const* d_in, const int* in_sizes, int n_in,
                              void* d_out, int out_size, void* d_ws, size_t ws_size,
                              hipStream_t stream) {
    const float* y = (const float*)d_in[0];
    float* out = (float*)d_out;
    dim3 grid(3, 24, 12);     // w-tiles, h-tiles, d-chunks (12*16 = 192 >= 191)
    dim3 block(32, 8, 1);
    jac_kernel<<<grid, block, 0, stream>>>(y, out);
}